// Round 6
// baseline (119.919 us; speedup 1.0000x reference)
//
#include <hip/hip_runtime.h>
#include <hip/hip_bf16.h>
#include <cstdint>

#define SEQ   1024
#define DOUT  1024
#define KDIM  1024
#define MTOT  4096      // BS*SEQ
#define WCROWS 1072     // 1024 W + 8 phi + 32 A2 + 8 zero

typedef __bf16 bf16x8 __attribute__((ext_vector_type(8)));
typedef float  f32x4  __attribute__((ext_vector_type(4)));

__device__ inline unsigned short f2bf(float f) {
  union { float f; unsigned u; } a; a.f = f;
  unsigned r = a.u + 0x7fff + ((a.u >> 16) & 1);   // RNE
  return (unsigned short)(r >> 16);
}

__device__ inline void gl16(const void* g, void* l) {
  __builtin_amdgcn_global_load_lds((__attribute__((address_space(1))) void*)g,
                                   (__attribute__((address_space(3))) void*)l, 16, 0, 0);
}

// fused prologue: [0,4096) cvt x; [4096,8384) build Wc; [8384,8512) B2T; 8512 thr
__global__ __launch_bounds__(256) void k_prep(const float4* __restrict__ x, ushort4* __restrict__ xb,
                                              const float* __restrict__ W, const float* __restrict__ phi,
                                              const float* __restrict__ la, const float* __restrict__ lb,
                                              unsigned short* __restrict__ Wc, unsigned short* __restrict__ B2T,
                                              const int* __restrict__ inst, int* __restrict__ thr) {
  int blk = blockIdx.x, tid = threadIdx.x;
  if (blk < 4096) {
    int i = blk * 256 + tid;
    float4 v = x[i];
    ushort4 o; o.x = f2bf(v.x); o.y = f2bf(v.y); o.z = f2bf(v.z); o.w = f2bf(v.w);
    xb[i] = o;
  } else if (blk < 8384) {
    int i = (blk - 4096) * 256 + tid;            // WCROWS*1024 exact
    int row = i >> 10, d = i & 1023;
    float v;
    if (row < 1024)       v = W[i];
    else if (row < 1032)  v = phi[d * 8 + (row - 1024)];
    else if (row < 1064)  { int kr = row - 1032; v = la[(kr >> 2) * 4096 + d * 4 + (kr & 3)]; }
    else                  v = 0.f;
    Wc[i] = f2bf(v);
  } else if (blk < 8512) {
    int i = (blk - 8384) * 256 + tid;            // 32768 exact: B2T[n][kr] = lb[kr][n]
    int n = i >> 5, kr = i & 31;
    B2T[i] = f2bf(lb[kr * 1024 + n]);
  } else {
    int b = tid >> 6, lane = tid & 63;           // wave b handles batch b
    int fo = 1 << 30, no = 0;
#pragma unroll
    for (int j = 0; j < 16; ++j) {
      int p = j * 64 + lane;
      int iv = inst[b * SEQ + p];
      if (iv > 0) fo = min(fo, p);
      no += iv;
    }
#pragma unroll
    for (int d = 1; d < 64; d <<= 1) { fo = min(fo, __shfl_xor(fo, d)); no += __shfl_xor(no, d); }
    if (lane == 0) thr[b] = (no > 0) ? fo + no : 0;
  }
}

// thin GEMM, 4-way K-split, double-buffered: mwzP[ks][c][row] over K-quarter ks
__global__ __launch_bounds__(256) void k_mwz(const unsigned short* __restrict__ xb,
                                             const unsigned short* __restrict__ Wc,
                                             float* __restrict__ mwzP) {
  __shared__ unsigned short As[2][64 * 32];
  __shared__ unsigned short Bs[2][48 * 32];
  int bm = blockIdx.x, ks = blockIdx.y;
  int t = threadIdx.x, wave = t >> 6, lane = t & 63;
  int quad = lane >> 4, lr = lane & 15;
  f32x4 acc[3];
#pragma unroll
  for (int i = 0; i < 3; ++i) acc[i] = (f32x4){0.f, 0.f, 0.f, 0.f};
  const unsigned short* aG = xb + (size_t)bm * 64 * KDIM + ks * 256;
  const unsigned short* bG = Wc + (size_t)1024 * KDIM + ks * 256;
  int r0 = t >> 2, c0 = (t & 3) * 8;

#define MWZ_STAGE(i) { int buf_ = (i) & 1; int kb_ = (i) * 32;                         \
    gl16(aG + (size_t)r0 * KDIM + kb_ + c0, &As[buf_][wave * 512]);                    \
    if (wave < 3) gl16(bG + (size_t)r0 * KDIM + kb_ + c0, &Bs[buf_][wave * 512]); }

  MWZ_STAGE(0)
  for (int i = 0; i < 8; ++i) {
    __syncthreads();
    if (i < 7) MWZ_STAGE(i + 1)
    int buf = i & 1;
    bf16x8 af = *(const bf16x8*)&As[buf][(wave * 16 + lr) * 32 + quad * 8];
#pragma unroll
    for (int ni = 0; ni < 3; ++ni) {
      bf16x8 bfr = *(const bf16x8*)&Bs[buf][(ni * 16 + lr) * 32 + quad * 8];
      acc[ni] = __builtin_amdgcn_mfma_f32_16x16x32_bf16(af, bfr, acc[ni], 0, 0, 0);
    }
  }
#pragma unroll
  for (int ni = 0; ni < 3; ++ni) {
    int c = ni * 16 + lr;
#pragma unroll
    for (int rg = 0; rg < 4; ++rg) {
      int row = bm * 64 + wave * 16 + quad * 4 + rg;
      if (c < 40) mwzP[(size_t)(ks * 40 + c) * MTOT + row] = acc[ni][rg];
    }
  }
}

// fused scan+gate: block (b,c): scan z_c*pad and pad over s, then
// gb[q][c] = softmax_k(mw)[c/4] * Tv / cnt   (e = max(thr,s+1)-1: own pos if
// s+1>=thr, else the single shared position thr-1)
__global__ __launch_bounds__(1024) void k_scan_gate(const float* __restrict__ mwzP,
                                                    const int* __restrict__ pad, const int* __restrict__ thr,
                                                    unsigned short* __restrict__ gb) {
  int b = blockIdx.x, c = blockIdx.y;
  int tid = threadIdx.x, wv = tid >> 6, lane = tid & 63;
  __shared__ float wsz[16], wsp[16];
  __shared__ float sv, spc;
  int q = b * SEQ + tid;
  float pm = (float)pad[q];
  float z = 0.f;
#pragma unroll
  for (int s = 0; s < 4; ++s) z += mwzP[(size_t)(s * 40 + 8 + c) * MTOT + q];
  z *= pm;
  float vz = z, vp = pm;
#pragma unroll
  for (int d = 1; d < 64; d <<= 1) {
    float oz = __shfl_up(vz, d), op = __shfl_up(vp, d);
    if (lane >= d) { vz += oz; vp += op; }
  }
  if (lane == 63) { wsz[wv] = vz; wsp[wv] = vp; }
  __syncthreads();
  if (wv == 0 && lane < 16) {
    float oz = wsz[lane], op = wsp[lane], sz = oz, sp = op;
#pragma unroll
    for (int d = 1; d < 16; d <<= 1) {
      float tz = __shfl_up(sz, d), tp = __shfl_up(sp, d);
      if (lane >= d) { sz += tz; sp += tp; }
    }
    wsz[lane] = sz - oz; wsp[lane] = sp - op;   // exclusive wave offsets
  }
  __syncthreads();
  vz += wsz[wv]; vp += wsp[wv];
  int th = thr[b];
  if (th > 0 && tid == th - 1) { sv = vz; spc = vp; }
  __syncthreads();
  unsigned short o = 0;
  if (pm != 0.f) {
    bool own = (tid + 1 >= th);
    float Tv  = own ? vz : sv;
    float cnt = own ? vp : spc;
    float C[8], mx = -1e30f;
#pragma unroll
    for (int k = 0; k < 8; ++k) {
      float m = 0.f;
#pragma unroll
      for (int s = 0; s < 4; ++s) m += mwzP[(size_t)(s * 40 + k) * MTOT + q];
      C[k] = m; mx = fmaxf(mx, m);
    }
    float sm = 0.f;
#pragma unroll
    for (int k = 0; k < 8; ++k) { C[k] = __expf(C[k] - mx); sm += C[k]; }
    o = f2bf(C[c >> 2] * Tv / (sm * cnt));
  }
  gb[(size_t)q * 32 + c] = o;
}

// BM=128 x BN=64 GEMM, 512 blocks (2/CU), double-buffered single-barrier K-loop.
// 33 compute iters: 32 over x@W^T, iter 32 = adapter (A=gb, B=B2T) — same code path.
__global__ __launch_bounds__(256) void k_gemm(const unsigned short* __restrict__ A,
                                              const unsigned short* __restrict__ Wc,
                                              const unsigned short* __restrict__ gb,
                                              const unsigned short* __restrict__ B2T,
                                              float* __restrict__ out,
                                              const float* __restrict__ bias) {
  __shared__ unsigned short As[2][128 * 32];  // 2 x 8 KB
  __shared__ unsigned short Bs[2][64 * 32];   // 2 x 4 KB
  int bm = blockIdx.x, bn = blockIdx.y;
  int t = threadIdx.x;
  int wave = t >> 6, lane = t & 63;
  int wr = wave >> 1, wc = wave & 1;          // wave: 64 rows x 32 cols
  int quad = lane >> 4, lr = lane & 15;
  f32x4 acc[4][2];
#pragma unroll
  for (int i = 0; i < 4; i++)
#pragma unroll
    for (int j = 0; j < 2; j++) acc[i][j] = (f32x4){0.f, 0.f, 0.f, 0.f};

  const unsigned short* aG = A + (size_t)bm * 128 * KDIM;
  const unsigned short* bG = Wc + (size_t)bn * 64 * KDIM;
  const unsigned short* gA = gb + (size_t)bm * 128 * 32;
  const unsigned short* gB = B2T + (size_t)bn * 64 * 32;
  int r0 = t >> 2, c0 = (t & 3) * 8;

#define GEMM_STAGE(i) { int buf_ = (i) & 1;                                            \
    if ((i) < 32) { int kb_ = (i) * 32;                                                \
      gl16(aG + (size_t)r0 * KDIM + kb_ + c0,        &As[buf_][wave * 512]);           \
      gl16(aG + (size_t)(r0 + 64) * KDIM + kb_ + c0, &As[buf_][2048 + wave * 512]);    \
      gl16(bG + (size_t)r0 * KDIM + kb_ + c0,        &Bs[buf_][wave * 512]);           \
    } else {                                                                           \
      gl16(gA + (size_t)r0 * 32 + c0,        &As[buf_][wave * 512]);                   \
      gl16(gA + (size_t)(r0 + 64) * 32 + c0, &As[buf_][2048 + wave * 512]);            \
      gl16(gB + (size_t)r0 * 32 + c0,        &Bs[buf_][wave * 512]);                   \
    } }

  GEMM_STAGE(0)
  for (int i = 0; i < 33; ++i) {
    __syncthreads();                 // drains stage(i) loads (in flight during iter i-1)
    if (i < 32) GEMM_STAGE(i + 1)
    int buf = i & 1;
    bf16x8 af[4], bfr[2];
#pragma unroll
    for (int mi = 0; mi < 4; mi++) af[mi]  = *(const bf16x8*)&As[buf][(wr * 64 + mi * 16 + lr) * 32 + quad * 8];
#pragma unroll
    for (int ni = 0; ni < 2; ni++) bfr[ni] = *(const bf16x8*)&Bs[buf][(wc * 32 + ni * 16 + lr) * 32 + quad * 8];
#pragma unroll
    for (int mi = 0; mi < 4; mi++)
#pragma unroll
      for (int ni = 0; ni < 2; ni++)
        acc[mi][ni] = __builtin_amdgcn_mfma_f32_16x16x32_bf16(af[mi], bfr[ni], acc[mi][ni], 0, 0, 0);
  }

  // epilogue: C/D layout col=lane&15, row=quad*4+reg
#pragma unroll
  for (int mi = 0; mi < 4; mi++) {
#pragma unroll
    for (int ni = 0; ni < 2; ni++) {
      int col = bn * 64 + wc * 32 + ni * 16 + lr;
      float bv = bias[col];
#pragma unroll
      for (int rg = 0; rg < 4; ++rg) {
        int row = bm * 128 + wr * 64 + mi * 16 + quad * 4 + rg;
        out[(size_t)row * DOUT + col] = acc[mi][ni][rg] + bv;
      }
    }
  }
}

extern "C" void kernel_launch(void* const* d_in, const int* in_sizes, int n_in,
                              void* d_out, int out_size, void* d_ws, size_t ws_size,
                              hipStream_t stream) {
  const float* x    = (const float*)d_in[0];
  const float* phi  = (const float*)d_in[1];
  const float* la   = (const float*)d_in[2];
  const float* lb   = (const float*)d_in[3];
  const float* W    = (const float*)d_in[4];
  const float* bias = (const float*)d_in[5];
  const int*   inst = (const int*)d_in[6];
  const int*   pad  = (const int*)d_in[7];
  float* out = (float*)d_out;

  char* ws = (char*)d_ws;
  unsigned short* xb  = (unsigned short*)ws;                   // 8388608 B
  unsigned short* Wc  = (unsigned short*)(ws + 8388608);       // 1072*1024*2 = 2195456 B
  unsigned short* B2T = (unsigned short*)(ws + 10584064);      // [1024][32] bf16 = 65536 B
  float* mwzP = (float*)(ws + 10649600);                       // [4][40][4096] f32 = 2621440 B
  unsigned short* gb  = (unsigned short*)(ws + 13271040);      // [4096][32] bf16 = 262144 B
  int*   thr  = (int*)(ws + 13533184);                         // 16 B

  hipLaunchKernelGGL(k_prep,      dim3(8513),   dim3(256),  0, stream,
                     (const float4*)x, (ushort4*)xb, W, phi, la, lb, Wc, B2T, inst, thr);
  hipLaunchKernelGGL(k_mwz,       dim3(64, 4),  dim3(256),  0, stream, xb, Wc, mwzP);
  hipLaunchKernelGGL(k_scan_gate, dim3(4, 32),  dim3(1024), 0, stream, mwzP, pad, thr, gb);
  hipLaunchKernelGGL(k_gemm,      dim3(32, 16), dim3(256),  0, stream, xb, Wc, gb, B2T, out, bias);
}